// Round 18
// baseline (319.575 us; speedup 1.0000x reference)
//
#include <hip/hip_runtime.h>
#include <stdint.h>

typedef __bf16 bf16;
typedef __bf16 bf16x8 __attribute__((ext_vector_type(8)));
typedef __bf16 bf16x4 __attribute__((ext_vector_type(4)));
typedef float  f32x4  __attribute__((ext_vector_type(4)));

#define T_SEQ  2048
#define NHEAD  16
#define DHEAD  128
#define DMODEL 2048
#define NQKV   3072   // 2048 Q | 512 K | 512 V per row
#define UNROLL _Pragma("unroll")

__device__ __forceinline__ void gload_lds16(const void* g, void* l) {
  __builtin_amdgcn_global_load_lds(
      (const __attribute__((address_space(1))) uint32_t*)g,
      (__attribute__((address_space(3))) uint32_t*)l, 16, 0, 0);
}

// ---------------- fused prep: x cast + 4 weight transposes ----------------
__device__ __forceinline__ void twt_body(const float* __restrict__ W,
                                         bf16* __restrict__ WT, int K, int N,
                                         int bx, int by, float (*t)[65]) {
  int k0 = bx * 64, n0 = by * 64;
  int r4 = threadIdx.x >> 6, c = threadIdx.x & 63;
#pragma unroll
  for (int i = 0; i < 16; i++) {
    int r = i * 4 + r4;
    t[r][c] = W[(size_t)(k0 + r) * N + n0 + c];
  }
  __syncthreads();
#pragma unroll
  for (int i = 0; i < 16; i++) {
    int r = i * 4 + r4;
    WT[(size_t)(n0 + r) * K + k0 + c] = (bf16)t[c][r];
  }
}

__global__ __launch_bounds__(256) void k_prep(const float* __restrict__ x,
                                              const float* __restrict__ Wq,
                                              const float* __restrict__ Wk,
                                              const float* __restrict__ Wv,
                                              const float* __restrict__ Wo,
                                              bf16* __restrict__ xb,
                                              bf16* __restrict__ WT,
                                              bf16* __restrict__ WoT) {
  __shared__ float t[64][65];
  const int blk = blockIdx.x;
  if (blk < 8192) {
    int i = (blk * 256 + threadIdx.x) * 4;
    float4 v = *(const float4*)(x + i);
    bf16x4 o = { (bf16)v.x, (bf16)v.y, (bf16)v.z, (bf16)v.w };
    *(bf16x4*)(xb + i) = o;
  } else if (blk < 9216) {
    int b = blk - 8192;
    twt_body(Wq, WT, 2048, 2048, b & 31, b >> 5, t);
  } else if (blk < 9472) {
    int b = blk - 9216;
    twt_body(Wk, WT + (size_t)2048 * 2048, 2048, 512, b & 31, b >> 5, t);
  } else if (blk < 9728) {
    int b = blk - 9472;
    twt_body(Wv, WT + (size_t)2560 * 2048, 2048, 512, b & 31, b >> 5, t);
  } else {
    int b = blk - 9728;
    twt_body(Wo, WoT, 2048, 2048, b & 31, b >> 5, t);
  }
}

// ---------------- post: V transpose only (RoPE fused into gemmQ epilogue) -------
__global__ __launch_bounds__(256) void k_post(const bf16* __restrict__ QKV,
                                              bf16* __restrict__ Vtg) {
  __shared__ bf16 t[64][65];
  const int bb = blockIdx.x;           // 512 blocks: 32 x 2 x 8
  int bx = bb & 31, by = (bb >> 5) & 1, g = bb >> 6;
  const int t0 = bx * 64, d0 = by * 64;
  const int b = g >> 2, kvh = g & 3;
  const bf16* src = QKV + (size_t)b * T_SEQ * NQKV + 2560 + kvh * DHEAD;
  bf16* dst = Vtg + ((size_t)(b * 4 + kvh) * 128 + d0) * T_SEQ + t0;
  const int r4 = threadIdx.x >> 6, c = threadIdx.x & 63;
#pragma unroll
  for (int i = 0; i < 16; i++) {
    int r = i * 4 + r4;
    t[r][c] = src[(size_t)(t0 + r) * NQKV + d0 + c];
  }
  __syncthreads();
#pragma unroll
  for (int i = 0; i < 16; i++) {
    int r = i * 4 + r4;
    dst[(size_t)r * T_SEQ + c] = t[c][r];
  }
}

// ---------------- GEMM Q: 128x384 8-phase, 256 blocks, RoPE fused epilogue -----
#define PHQ(BUF, P, RB, VMW, STAGE) do {                                                  \
    bf16x8 ak0 = rdA(BUF, P, 0), ak1 = rdA(BUF, P, 1);                                    \
    if (RB) {                                                                             \
      UNROLL for (int n = 0; n < 6; n++) { b0[n] = rdB(BUF, 0, n); b1[n] = rdB(BUF, 1, n); } \
    }                                                                                     \
    STAGE                                                                                 \
    __builtin_amdgcn_sched_barrier(0);                                                    \
    __builtin_amdgcn_s_barrier();                                                         \
    asm volatile("s_waitcnt lgkmcnt(0)" ::: "memory");                                    \
    __builtin_amdgcn_sched_barrier(0);                                                    \
    __builtin_amdgcn_s_setprio(1);                                                        \
    UNROLL for (int n = 0; n < 6; n++) {                                                  \
      acc[P][n] = __builtin_amdgcn_mfma_f32_16x16x32_bf16(ak0, b0[n], acc[P][n], 0, 0, 0);\
      acc[P][n] = __builtin_amdgcn_mfma_f32_16x16x32_bf16(ak1, b1[n], acc[P][n], 0, 0, 0);\
    }                                                                                     \
    __builtin_amdgcn_s_setprio(0);                                                        \
    if (VMW) { asm volatile("s_waitcnt vmcnt(6)" ::: "memory"); }                         \
    __builtin_amdgcn_sched_barrier(0);                                                    \
    __builtin_amdgcn_s_barrier();                                                         \
  } while (0)

__global__ __launch_bounds__(512) void k_gemmQ(const bf16* __restrict__ A,
                                               const bf16* __restrict__ BT,
                                               bf16* __restrict__ C,
                                               int M, int N, int K) {
  __shared__ __align__(16) bf16 L[2][4][8192];     // [buf][A,B0,B1,B2][128*64]
  const int nwg = gridDim.x * gridDim.y;           // 256
  const int orig = blockIdx.y * gridDim.x + blockIdx.x;
  const int tile = (orig & 7) * (nwg >> 3) + (orig >> 3);
  const int m0 = (tile % gridDim.x) * 128, n0 = (tile / gridDim.x) * 384;
  const int tid = threadIdx.x;
  const int lane = tid & 63, w = tid >> 6;
  const int wr = w >> 2, wc = w & 3;               // 2M x 4N waves; wave out 64x96
  const int l15 = lane & 15, lg = lane >> 4;
  const int srow = tid >> 3;                       // 0..63
  const int scol = ((tid & 7) ^ (srow & 7)) * 8;   // inverse-swizzled source col
  const int NKT = K >> 6;

  f32x4 acc[4][6] = {};
  bf16x8 b0[6], b1[6];

  auto stA = [&](int buf, int kt) {
    const bf16* g = A + (size_t)(m0 + srow) * K + kt * 64 + scol;
    bf16* lb = &L[buf][0][w * 512];
    gload_lds16(g, lb);
    gload_lds16(g + (size_t)64 * K, lb + 4096);
  };
  auto stB = [&](int buf, int c, int kt) {
    const bf16* g = BT + (size_t)(n0 + c * 128 + srow) * K + kt * 64 + scol;
    bf16* lb = &L[buf][1 + c][w * 512];
    gload_lds16(g, lb);
    gload_lds16(g + (size_t)64 * K, lb + 4096);
  };
  auto rdA = [&](int buf, int m, int kk) -> bf16x8 {
    int r = wr * 64 + m * 16 + l15;
    return *(const bf16x8*)((const char*)&L[buf][0][0] + r * 128 +
                            (((kk * 4 + lg) ^ (r & 7)) << 4));
  };
  auto rdB = [&](int buf, int kk, int n) -> bf16x8 {
    int rr = wc * 96 + n * 16 + l15;
    return *(const bf16x8*)((const char*)&L[buf][1 + (rr >> 7)][0] + (rr & 127) * 128 +
                            (((kk * 4 + lg) ^ (rr & 7)) << 4));
  };

  stA(0, 0);
  stB(0, 0, 0); stB(0, 1, 0); stB(0, 2, 0);
  stB(1, 0, 1); stB(1, 1, 1); stB(1, 2, 1);
  asm volatile("s_waitcnt vmcnt(6)" ::: "memory");
  __builtin_amdgcn_sched_barrier(0);
  __builtin_amdgcn_s_barrier();

  for (int it = 0; it < (NKT >> 1); ++it) {
    const int t1 = 2 * it + 1;
    const int t2 = (t1 + 1 < NKT) ? t1 + 1 : NKT - 1;
    const int t3 = (t1 + 2 < NKT) ? t1 + 2 : NKT - 1;
    PHQ(0, 0, 1, 0, stA(1, t1););
    PHQ(0, 1, 0, 0, stB(0, 0, t2););
    PHQ(0, 2, 0, 0, stB(0, 1, t2););
    PHQ(0, 3, 0, 1, stB(0, 2, t2););
    PHQ(1, 0, 1, 0, stA(0, t2););
    PHQ(1, 1, 0, 0, stB(1, 0, t3););
    PHQ(1, 2, 0, 0, stB(1, 1, t3););
    PHQ(1, 3, 0, 1, stB(1, 2, t3););
  }

  // Epilogue with fused RoPE on Q|K columns (< 2560).
  const float L2B = 0.20762050593046007f;  // log2(10000)/64
  const int r0 = m0 + wr * 64 + lg * 4;
  const int c0 = n0 + wc * 96 + l15;
  UNROLL for (int n = 0; n < 6; n++) {
    const int col = c0 + n * 16;
    const bool rope = col < 2560;
    const float inv = exp2f(-(float)((col & 127) >> 1) * L2B);
    UNROLL for (int m = 0; m < 4; m++)
      UNROLL for (int i = 0; i < 4; i++) {
        float v = acc[m][n][i];
        float p = __shfl_xor(v, 1);
        float outv = v;
        if (rope) {
          int t = (r0 + m * 16 + i) & (T_SEQ - 1);
          float cs, sn;
          __sincosf((float)t * inv, &sn, &cs);
          outv = (col & 1) ? (p * sn + v * cs) : (v * cs - p * sn);
        }
        C[(size_t)(r0 + m * 16 + i) * N + col] = (bf16)outv;
      }
  }
}

// ---------------- GEMM B: 256x128 8-phase (full-machine grid for out-proj) ------
#define PH2(BUF, P, RB, VMW, STAGE) do {                                                  \
    bf16x8 a0k0 = rdA(BUF, 2*(P),     0), a0k1 = rdA(BUF, 2*(P),     1);                  \
    bf16x8 a1k0 = rdA(BUF, 2*(P) + 1, 0), a1k1 = rdA(BUF, 2*(P) + 1, 1);                  \
    if (RB) {                                                                             \
      UNROLL for (int n = 0; n < 2; n++) { b0[n] = rdB(BUF, 0, n); b1[n] = rdB(BUF, 1, n); } \
    }                                                                                     \
    STAGE                                                                                 \
    __builtin_amdgcn_sched_barrier(0);                                                    \
    __builtin_amdgcn_s_barrier();                                                         \
    asm volatile("s_waitcnt lgkmcnt(0)" ::: "memory");                                    \
    __builtin_amdgcn_sched_barrier(0);                                                    \
    __builtin_amdgcn_s_setprio(1);                                                        \
    UNROLL for (int n = 0; n < 2; n++) {                                                  \
      acc[2*(P)][n]   = __builtin_amdgcn_mfma_f32_16x16x32_bf16(a0k0, b0[n], acc[2*(P)][n], 0, 0, 0);     \
      acc[2*(P)][n]   = __builtin_amdgcn_mfma_f32_16x16x32_bf16(a0k1, b1[n], acc[2*(P)][n], 0, 0, 0);     \
      acc[2*(P)+1][n] = __builtin_amdgcn_mfma_f32_16x16x32_bf16(a1k0, b0[n], acc[2*(P)+1][n], 0, 0, 0);   \
      acc[2*(P)+1][n] = __builtin_amdgcn_mfma_f32_16x16x32_bf16(a1k1, b1[n], acc[2*(P)+1][n], 0, 0, 0);   \
    }                                                                                     \
    __builtin_amdgcn_s_setprio(0);                                                        \
    if (VMW) { asm volatile("s_waitcnt vmcnt(2)" ::: "memory"); }                         \
    __builtin_amdgcn_sched_barrier(0);                                                    \
    __builtin_amdgcn_s_barrier();                                                         \
  } while (0)

__global__ __launch_bounds__(512) void k_gemm3(const bf16* __restrict__ A,
                                               const bf16* __restrict__ BT,
                                               float* __restrict__ C,
                                               int M, int N, int K) {
  __shared__ __align__(16) bf16 L[2][3][8192];     // [buf][A0,A1,B][128*64]
  const int nwg = gridDim.x * gridDim.y;
  const int orig = blockIdx.y * gridDim.x + blockIdx.x;
  const int tile = (orig & 7) * (nwg >> 3) + (orig >> 3);   // nwg % 8 == 0
  const int m0 = (tile % gridDim.x) * 256, n0 = (tile / gridDim.x) * 128;
  const int tid = threadIdx.x;
  const int lane = tid & 63, w = tid >> 6;
  const int wr = w >> 2, wc = w & 3;
  const int l15 = lane & 15, lg = lane >> 4;
  const int srow = tid >> 3;
  const int scol = ((tid & 7) ^ (srow & 7)) * 8;
  const int NKT = K >> 6;

  f32x4 acc[8][2] = {};
  bf16x8 b0[2], b1[2];

  auto stA = [&](int buf, int half, int kt) {
    const bf16* g = A + (size_t)(m0 + half * 128 + srow) * K + kt * 64 + scol;
    bf16* lb = &L[buf][half][w * 512];
    gload_lds16(g, lb);
    gload_lds16(g + (size_t)64 * K, lb + 4096);
  };
  auto stB = [&](int buf, int kt) {
    const bf16* g = BT + (size_t)(n0 + srow) * K + kt * 64 + scol;
    bf16* lb = &L[buf][2][w * 512];
    gload_lds16(g, lb);
    gload_lds16(g + (size_t)64 * K, lb + 4096);
  };
  auto rdA = [&](int buf, int fr, int kk) -> bf16x8 {
    int r = fr * 16 + l15;
    return *(const bf16x8*)((const char*)&L[buf][wr][0] + r * 128 +
                            (((kk * 4 + lg) ^ (r & 7)) << 4));
  };
  auto rdB = [&](int buf, int kk, int n) -> bf16x8 {
    int rr = wc * 32 + n * 16 + l15;
    return *(const bf16x8*)((const char*)&L[buf][2][0] + rr * 128 +
                            (((kk * 4 + lg) ^ (rr & 7)) << 4));
  };

  stA(0, 0, 0); stA(0, 1, 0); stB(0, 0);
  stB(1, 1);
  asm volatile("s_waitcnt vmcnt(2)" ::: "memory");
  __builtin_amdgcn_sched_barrier(0);
  __builtin_amdgcn_s_barrier();

  for (int it = 0; it < (NKT >> 1); ++it) {
    const int t1 = 2 * it + 1;
    const int t2 = (t1 + 1 < NKT) ? t1 + 1 : NKT - 1;
    const int t3 = (t1 + 2 < NKT) ? t1 + 2 : NKT - 1;
    PH2(0, 0, 1, 0, stA(1, 0, t1););
    PH2(0, 1, 0, 0, stA(1, 1, t1););
    PH2(0, 2, 0, 0, stB(0, t2););
    PH2(0, 3, 0, 1, ;);
    PH2(1, 0, 1, 0, stA(0, 0, t2););
    PH2(1, 1, 0, 0, stA(0, 1, t2););
    PH2(1, 2, 0, 0, stB(1, t3););
    PH2(1, 3, 0, 1, ;);
  }

  const int r0 = m0 + wr * 128 + lg * 4;
  const int c0 = n0 + wc * 32 + l15;
  UNROLL for (int m = 0; m < 8; m++)
    UNROLL for (int n = 0; n < 2; n++)
      UNROLL for (int i = 0; i < 4; i++)
        C[(size_t)(r0 + m * 16 + i) * N + (c0 + n * 16)] = acc[m][n][i];
}

// ---------------- flash attention (causal, GQA), head-paired, shared-operand ----
// Round-13 structure; Ps shrunk to [4][16][64] with XOR swizzle (byte^=(q&7)<<4):
// LDS = 40960 exactly -> 4 blocks/CU; __launch_bounds__(256,4) caps VGPR at 128.
#define PSOFF(q, byteoff) ((q) * 128 + ((byteoff) ^ (((q) & 7) << 4)))

#define COMPUTE2(kt) do {                                                                 \
    f32x4 sA_[4] = {}, sB_[4] = {};                                                       \
    const char* ks_ = (const char*)Ks;                                                    \
    __builtin_amdgcn_s_setprio(1);                                                        \
    UNROLL for (int kk = 0; kk < 4; kk++)                                                 \
      UNROLL for (int n = 0; n < 4; n++) {                                                \
        int row_ = n * 16 + l15;                                                          \
        int cb_ = (kk * 64 + lg * 16) ^ ((row_ & 7) << 4);                                \
        bf16x8 kf_ = *(const bf16x8*)(ks_ + row_ * 256 + cb_);                            \
        sA_[n] = __builtin_amdgcn_mfma_f32_16x16x32_bf16(kf_, qA[kk], sA_[n], 0, 0, 0);   \
        sB_[n] = __builtin_amdgcn_mfma_f32_16x16x32_bf16(kf_, qB[kk], sB_[n], 0, 0, 0);   \
      }                                                                                   \
    __builtin_amdgcn_s_setprio(0);                                                        \
    __syncthreads();                       /* bar1: QK reads done, V(kt) landed */        \
    if ((kt) + 1 < NT) issueK((kt) + 1);   /* refill Ks; flies under SM+PV */             \
    float vmA_ = -1e30f, vmB_ = -1e30f;                                                   \
    if ((kt) == qt) {                                                                     \
      UNROLL for (int n = 0; n < 4; n++)                                                  \
        UNROLL for (int i = 0; i < 4; i++) {                                              \
          if ((kt) * 64 + n * 16 + lg * 4 + i > qglob) {                                  \
            sA_[n][i] = -1e30f; sB_[n][i] = -1e30f;                                       \
          }                                                                               \
          vmA_ = fmaxf(vmA_, sA_[n][i]);                                                  \
          vmB_ = fmaxf(vmB_, sB_[n][i]);                                                  \
        }                                                                                 \
    } else {                                                                              \
      UNROLL for (int n = 0; n < 4; n++)                                                  \
        UNROLL for (int i = 0; i < 4; i++) {                                              \
          vmA_ = fmaxf(vmA_, sA_[n][i]);                                                  \
          vmB_ = fmaxf(vmB_, sB_[n][i]);                                                  \
        }                                                                                 \
    }                                                                                     \
    vmA_ = fmaxf(vmA_, __shfl_xor(vmA_, 16));                                             \
    vmA_ = fmaxf(vmA_, __shfl_xor(vmA_, 32));                                             \
    vmB_ = fmaxf(vmB_, __shfl_xor(vmB_, 16));                                             \
    vmB_ = fmaxf(vmB_, __shfl_xor(vmB_, 32));                                             \
    if (!__all((vmA_ <= mA + 8.0f) && (vmB_ <= mB + 8.0f))) {                             \
      float mnA_ = fmaxf(mA, vmA_), mnB_ = fmaxf(mB, vmB_);                               \
      float alA_ = __builtin_amdgcn_exp2f(mA - mnA_);                                     \
      float alB_ = __builtin_amdgcn_exp2f(mB - mnB_);                                     \
      mA = mnA_; mB = mnB_;                                                               \
      lA *= alA_; lB *= alB_;                                                             \
      UNROLL for (int i = 0; i < 4; i++) {                                                \
        int src_ = (lane & 48) + ((lane >> 2) & 12) + i;                                  \
        float aA_ = __shfl(alA_, src_);                                                   \
        float aB_ = __shfl(alB_, src_);                                                   \
        UNROLL for (int n = 0; n < 8; n++) { oA[n][i] *= aA_; oB[n][i] *= aB_; }          \
      }                                                                                   \
    }                                                                                     \
    bf16x8 paA0_, paA1_, paB0_, paB1_;                                                    \
    {                                                                                     \
      float rs_ = 0.f;                                                                    \
      UNROLL for (int n = 0; n < 4; n++) {                                                \
        bf16x4 pk_;                                                                       \
        UNROLL for (int i = 0; i < 4; i++) {                                              \
          float pv_ = __builtin_amdgcn_exp2f(sA_[n][i] - mA);                             \
          rs_ += pv_;                                                                     \
          pk_[i] = (bf16)pv_;                                                             \
        }                                                                                 \
        *(bf16x4*)(pw_ + PSOFF(l15, n * 32 + lg * 8)) = pk_;                              \
      }                                                                                   \
      rs_ += __shfl_xor(rs_, 16);                                                         \
      rs_ += __shfl_xor(rs_, 32);                                                         \
      lA += rs_;                                                                          \
      paA0_ = *(const bf16x8*)(pw_ + PSOFF(l15, lg * 16));                                \
      paA1_ = *(const bf16x8*)(pw_ + PSOFF(l15, 64 + lg * 16));                           \
    }                                                                                     \
    {                                                                                     \
      float rs_ = 0.f;                                                                    \
      UNROLL for (int n = 0; n < 4; n++) {                                                \
        bf16x4 pk_;                                                                       \
        UNROLL for (int i = 0; i < 4; i++) {                                              \
          float pv_ = __builtin_amdgcn_exp2f(sB_[n][i] - mB);                             \
          rs_ += pv_;                                                                     \
          pk_[i] = (bf16)pv_;                                                             \
        }                                                                                 \
        *(bf16x4*)(pw_ + PSOFF(l15, n * 32 + lg * 8)) = pk_;                              \
      }                                                                                   \
      rs_ += __shfl_xor(rs_, 16);                                                         \
      rs_ += __shfl_xor(rs_, 32);                                                         \
      lB += rs_;                                                                          \
      paB0_ = *(const bf16x8*)(pw_ + PSOFF(l15, lg * 16));                                \
      paB1_ = *(const bf16x8*)(pw_ + PSOFF(l15, 64 + lg * 16));                           \
    }                                                                                     \
    const char* vs_ = (const char*)Vs;                                                    \
    __builtin_amdgcn_s_setprio(1);                                                        \
    UNROLL for (int n = 0; n < 8; n++) {                                                  \
      int d_ = n * 16 + l15;                                                              \
      bf16x8 vf0_ = *(const bf16x8*)(vs_ + d_ * 128 + (((lg) ^ (d_ & 7)) << 4));          \
      oA[n] = __builtin_amdgcn_mfma_f32_16x16x32_bf16(paA0_, vf0_, oA[n], 0, 0, 0);       \
      oB[n] = __builtin_amdgcn_mfma_f32_16x16x32_bf16(paB0_, vf0_, oB[n], 0, 0, 0);       \
      bf16x8 vf1_ = *(const bf16x8*)(vs_ + d_ * 128 + (((4 + lg) ^ (d_ & 7)) << 4));      \
      oA[n] = __builtin_amdgcn_mfma_f32_16x16x32_bf16(paA1_, vf1_, oA[n], 0, 0, 0);       \
      oB[n] = __builtin_amdgcn_mfma_f32_16x16x32_bf16(paB1_, vf1_, oB[n], 0, 0, 0);       \
    }                                                                                     \
    __builtin_amdgcn_s_setprio(0);                                                        \
    __syncthreads();                       /* bar2: PV reads done, K(kt+1) landed */      \
    if ((kt) + 1 < NT) issueV((kt) + 1);   /* refill Vs; flies under next QK */           \
  } while (0)

__global__ __launch_bounds__(256, 4) void k_flash(const bf16* __restrict__ QKV,
                                                  const bf16* __restrict__ Vtg,
                                                  bf16* __restrict__ AO) {
  __shared__ __align__(16) bf16 Ks[64 * 128];      // [kv row]*256B, chunk XOR (row&7)
  __shared__ __align__(16) bf16 Vs[128 * 64];      // [d row]*128B,  chunk XOR (d&7)
  __shared__ __align__(16) bf16 Ps[4][16][64];     // 128B rows, XOR (q&7)<<4 swizzle
  const int orig = blockIdx.y * 32 + blockIdx.x;
  const int fin  = ((orig & 7) << 6) | (orig >> 3);
  const int bhp  = fin >> 5;                 // b*8 + kvh*2 + hp
  const int qt   = 31 - (fin & 31);
  const int b = bhp >> 3, kvh = (bhp >> 1) & 3, hp = bhp & 1;
  const int h0 = kvh * 4 + hp * 2, h1 = h0 + 1;
  const int tid = threadIdx.x, lane = tid & 63, w = tid >> 6;
  const int l15 = lane & 15, lg = lane >> 4;
  const int qglob = qt * 64 + w * 16 + l15;
  const float qs = 0.12753102f;              // (1/sqrt(128)) * log2(e)
  char* pw_ = (char*)&Ps[w][0][0];

  bf16x8 qA[4], qB[4];
  {
    const size_t qoA = (size_t)(b * T_SEQ + qt * 64 + w * 16 + l15) * NQKV + h0 * DHEAD;
    const size_t qoB = (size_t)(b * T_SEQ + qt * 64 + w * 16 + l15) * NQKV + h1 * DHEAD;
    UNROLL for (int kk = 0; kk < 4; kk++) {
      bf16x8 a = *(const bf16x8*)(QKV + qoA + kk * 32 + lg * 8);
      bf16x8 bb = *(const bf16x8*)(QKV + qoB + kk * 32 + lg * 8);
      UNROLL for (int j = 0; j < 8; j++) {
        a[j] = (bf16)((float)a[j] * qs);
        bb[j] = (bf16)((float)bb[j] * qs);
      }
      qA[kk] = a; qB[kk] = bb;
    }
  }

  f32x4 oA[8] = {}, oB[8] = {};
  float mA = -1e30f, mB = -1e30f, lA = 0.f, lB = 0.f;

  const bf16* Kbase = QKV + (size_t)b * T_SEQ * NQKV + DMODEL + kvh * DHEAD;
  const bf16* Vbase = Vtg + (size_t)(b * 4 + kvh) * 128 * T_SEQ;

  auto issueK = [&](int kt) {
    UNROLL for (int i = 0; i < 4; i++) {
      int row = w * 16 + i * 4 + lg;
      int col = (l15 ^ (row & 7)) * 8;
      gload_lds16(Kbase + (size_t)(kt * 64 + row) * NQKV + col,
                  Ks + (w * 4 + i) * 512);
    }
  };
  auto issueV = [&](int kt) {
    UNROLL for (int i = 0; i < 4; i++) {
      int d = (w * 4 + i) * 8 + (lane >> 3);
      int u = lane & 7;
      gload_lds16(Vbase + (size_t)d * T_SEQ + kt * 64 + ((u ^ (d & 7)) * 8),
                  Vs + (w * 4 + i) * 512);
    }
  };

  issueK(0);
  issueV(0);
  __syncthreads();

  const int NT = qt + 1;
  for (int kt = 0; kt < NT; kt++) {
    COMPUTE2(kt);
  }

  {
    const size_t ob0 = (size_t)(b * T_SEQ + qt * 64 + w * 16 + lg * 4) * DMODEL + h0 * DHEAD + l15;
    const size_t ob1 = (size_t)(b * T_SEQ + qt * 64 + w * 16 + lg * 4) * DMODEL + h1 * DHEAD + l15;
    UNROLL for (int i = 0; i < 4; i++) {
      int src = (lane & 48) + ((lane >> 2) & 12) + i;
      float invA = 1.0f / __shfl(lA, src);
      float invB = 1.0f / __shfl(lB, src);
      UNROLL for (int n = 0; n < 8; n++) {
        AO[ob0 + (size_t)i * DMODEL + n * 16] = (bf16)(oA[n][i] * invA);
        AO[ob1 + (size_t)i * DMODEL + n * 16] = (bf16)(oB[n][i] * invB);
      }
    }
  }
}

extern "C" void kernel_launch(void* const* d_in, const int* in_sizes, int n_in,
                              void* d_out, int out_size, void* d_ws, size_t ws_size,
                              hipStream_t stream) {
  const float* x  = (const float*)d_in[0];
  const float* Wq = (const float*)d_in[1];
  const float* Wk = (const float*)d_in[2];
  const float* Wv = (const float*)d_in[3];
  const float* Wo = (const float*)d_in[4];
  char* ws = (char*)d_ws;
  bf16* xb  = (bf16*)ws;                                             // 4096x2048
  bf16* WT  = (bf16*)(ws + 16777216ull);                             // 3072x2048 (WqT|WkT|WvT)
  bf16* WoT = (bf16*)(ws + 16777216ull + 12582912ull);               // 2048x2048
  bf16* QKV = (bf16*)(ws + 16777216ull + 12582912ull + 8388608ull);  // 4096x3072
  bf16* AO  = (bf16*)(ws + 16777216ull + 12582912ull + 8388608ull + 25165824ull); // 4096x2048
  bf16* Vtg = WT;   // WT is dead after the QKV GEMM; reuse first 4 MB for V^T
  float* out = (float*)d_out;

  k_prep<<<10752, 256, 0, stream>>>(x, Wq, Wk, Wv, Wo, xb, WT, WoT);
  k_gemmQ<<<dim3(32, 8), 512, 0, stream>>>(xb, WT, QKV, 4096, 3072, 2048);
  k_post<<<512, 256, 0, stream>>>(QKV, Vtg);
  k_flash<<<dim3(32, 16), 256, 0, stream>>>(QKV, Vtg, AO);
  k_gemm3<<<dim3(16, 16), 512, 0, stream>>>(AO, WoT, out, 4096, 2048, 2048);
}

// Round 19
// 188.449 us; speedup vs baseline: 1.6958x; 1.6958x over previous
//
#include <hip/hip_runtime.h>
#include <stdint.h>

typedef __bf16 bf16;
typedef __bf16 bf16x8 __attribute__((ext_vector_type(8)));
typedef __bf16 bf16x4 __attribute__((ext_vector_type(4)));
typedef float  f32x4  __attribute__((ext_vector_type(4)));

#define T_SEQ  2048
#define NHEAD  16
#define DHEAD  128
#define DMODEL 2048
#define NQKV   3072   // 2048 Q | 512 K | 512 V per row
#define UNROLL _Pragma("unroll")

__device__ __forceinline__ void gload_lds16(const void* g, void* l) {
  __builtin_amdgcn_global_load_lds(
      (const __attribute__((address_space(1))) uint32_t*)g,
      (__attribute__((address_space(3))) uint32_t*)l, 16, 0, 0);
}

// ---------------- fused prep: x cast + 4 weight transposes ----------------
__device__ __forceinline__ void twt_body(const float* __restrict__ W,
                                         bf16* __restrict__ WT, int K, int N,
                                         int bx, int by, float (*t)[65]) {
  int k0 = bx * 64, n0 = by * 64;
  int r4 = threadIdx.x >> 6, c = threadIdx.x & 63;
#pragma unroll
  for (int i = 0; i < 16; i++) {
    int r = i * 4 + r4;
    t[r][c] = W[(size_t)(k0 + r) * N + n0 + c];
  }
  __syncthreads();
#pragma unroll
  for (int i = 0; i < 16; i++) {
    int r = i * 4 + r4;
    WT[(size_t)(n0 + r) * K + k0 + c] = (bf16)t[c][r];
  }
}

__global__ __launch_bounds__(256) void k_prep(const float* __restrict__ x,
                                              const float* __restrict__ Wq,
                                              const float* __restrict__ Wk,
                                              const float* __restrict__ Wv,
                                              const float* __restrict__ Wo,
                                              bf16* __restrict__ xb,
                                              bf16* __restrict__ WT,
                                              bf16* __restrict__ WoT) {
  __shared__ float t[64][65];
  const int blk = blockIdx.x;
  if (blk < 8192) {
    int i = (blk * 256 + threadIdx.x) * 4;
    float4 v = *(const float4*)(x + i);
    bf16x4 o = { (bf16)v.x, (bf16)v.y, (bf16)v.z, (bf16)v.w };
    *(bf16x4*)(xb + i) = o;
  } else if (blk < 9216) {
    int b = blk - 8192;
    twt_body(Wq, WT, 2048, 2048, b & 31, b >> 5, t);
  } else if (blk < 9472) {
    int b = blk - 9216;
    twt_body(Wk, WT + (size_t)2048 * 2048, 2048, 512, b & 31, b >> 5, t);
  } else if (blk < 9728) {
    int b = blk - 9472;
    twt_body(Wv, WT + (size_t)2560 * 2048, 2048, 512, b & 31, b >> 5, t);
  } else {
    int b = blk - 9728;
    twt_body(Wo, WoT, 2048, 2048, b & 31, b >> 5, t);
  }
}

// ---------------- post: V transpose only (RoPE fused into gemmQ epilogue) -------
__global__ __launch_bounds__(256) void k_post(const bf16* __restrict__ QKV,
                                              bf16* __restrict__ Vtg) {
  __shared__ bf16 t[64][65];
  const int bb = blockIdx.x;           // 512 blocks: 32 x 2 x 8
  int bx = bb & 31, by = (bb >> 5) & 1, g = bb >> 6;
  const int t0 = bx * 64, d0 = by * 64;
  const int b = g >> 2, kvh = g & 3;
  const bf16* src = QKV + (size_t)b * T_SEQ * NQKV + 2560 + kvh * DHEAD;
  bf16* dst = Vtg + ((size_t)(b * 4 + kvh) * 128 + d0) * T_SEQ + t0;
  const int r4 = threadIdx.x >> 6, c = threadIdx.x & 63;
#pragma unroll
  for (int i = 0; i < 16; i++) {
    int r = i * 4 + r4;
    t[r][c] = src[(size_t)(t0 + r) * NQKV + d0 + c];
  }
  __syncthreads();
#pragma unroll
  for (int i = 0; i < 16; i++) {
    int r = i * 4 + r4;
    dst[(size_t)r * T_SEQ + c] = t[c][r];
  }
}

// ---------------- GEMM Q: 128x384 8-phase, 256 blocks, RoPE fused epilogue -----
#define PHQ(BUF, P, RB, VMW, STAGE) do {                                                  \
    bf16x8 ak0 = rdA(BUF, P, 0), ak1 = rdA(BUF, P, 1);                                    \
    if (RB) {                                                                             \
      UNROLL for (int n = 0; n < 6; n++) { b0[n] = rdB(BUF, 0, n); b1[n] = rdB(BUF, 1, n); } \
    }                                                                                     \
    STAGE                                                                                 \
    __builtin_amdgcn_sched_barrier(0);                                                    \
    __builtin_amdgcn_s_barrier();                                                         \
    asm volatile("s_waitcnt lgkmcnt(0)" ::: "memory");                                    \
    __builtin_amdgcn_sched_barrier(0);                                                    \
    __builtin_amdgcn_s_setprio(1);                                                        \
    UNROLL for (int n = 0; n < 6; n++) {                                                  \
      acc[P][n] = __builtin_amdgcn_mfma_f32_16x16x32_bf16(ak0, b0[n], acc[P][n], 0, 0, 0);\
      acc[P][n] = __builtin_amdgcn_mfma_f32_16x16x32_bf16(ak1, b1[n], acc[P][n], 0, 0, 0);\
    }                                                                                     \
    __builtin_amdgcn_s_setprio(0);                                                        \
    if (VMW) { asm volatile("s_waitcnt vmcnt(6)" ::: "memory"); }                         \
    __builtin_amdgcn_sched_barrier(0);                                                    \
    __builtin_amdgcn_s_barrier();                                                         \
  } while (0)

__global__ __launch_bounds__(512) void k_gemmQ(const bf16* __restrict__ A,
                                               const bf16* __restrict__ BT,
                                               bf16* __restrict__ C,
                                               int M, int N, int K) {
  __shared__ __align__(16) bf16 L[2][4][8192];     // [buf][A,B0,B1,B2][128*64]
  const int nwg = gridDim.x * gridDim.y;           // 256
  const int orig = blockIdx.y * gridDim.x + blockIdx.x;
  const int tile = (orig & 7) * (nwg >> 3) + (orig >> 3);
  const int m0 = (tile % gridDim.x) * 128, n0 = (tile / gridDim.x) * 384;
  const int tid = threadIdx.x;
  const int lane = tid & 63, w = tid >> 6;
  const int wr = w >> 2, wc = w & 3;               // 2M x 4N waves; wave out 64x96
  const int l15 = lane & 15, lg = lane >> 4;
  const int srow = tid >> 3;                       // 0..63
  const int scol = ((tid & 7) ^ (srow & 7)) * 8;   // inverse-swizzled source col
  const int NKT = K >> 6;

  f32x4 acc[4][6] = {};
  bf16x8 b0[6], b1[6];

  auto stA = [&](int buf, int kt) {
    const bf16* g = A + (size_t)(m0 + srow) * K + kt * 64 + scol;
    bf16* lb = &L[buf][0][w * 512];
    gload_lds16(g, lb);
    gload_lds16(g + (size_t)64 * K, lb + 4096);
  };
  auto stB = [&](int buf, int c, int kt) {
    const bf16* g = BT + (size_t)(n0 + c * 128 + srow) * K + kt * 64 + scol;
    bf16* lb = &L[buf][1 + c][w * 512];
    gload_lds16(g, lb);
    gload_lds16(g + (size_t)64 * K, lb + 4096);
  };
  auto rdA = [&](int buf, int m, int kk) -> bf16x8 {
    int r = wr * 64 + m * 16 + l15;
    return *(const bf16x8*)((const char*)&L[buf][0][0] + r * 128 +
                            (((kk * 4 + lg) ^ (r & 7)) << 4));
  };
  auto rdB = [&](int buf, int kk, int n) -> bf16x8 {
    int rr = wc * 96 + n * 16 + l15;
    return *(const bf16x8*)((const char*)&L[buf][1 + (rr >> 7)][0] + (rr & 127) * 128 +
                            (((kk * 4 + lg) ^ (rr & 7)) << 4));
  };

  stA(0, 0);
  stB(0, 0, 0); stB(0, 1, 0); stB(0, 2, 0);
  stB(1, 0, 1); stB(1, 1, 1); stB(1, 2, 1);
  asm volatile("s_waitcnt vmcnt(6)" ::: "memory");
  __builtin_amdgcn_sched_barrier(0);
  __builtin_amdgcn_s_barrier();

  for (int it = 0; it < (NKT >> 1); ++it) {
    const int t1 = 2 * it + 1;
    const int t2 = (t1 + 1 < NKT) ? t1 + 1 : NKT - 1;
    const int t3 = (t1 + 2 < NKT) ? t1 + 2 : NKT - 1;
    PHQ(0, 0, 1, 0, stA(1, t1););
    PHQ(0, 1, 0, 0, stB(0, 0, t2););
    PHQ(0, 2, 0, 0, stB(0, 1, t2););
    PHQ(0, 3, 0, 1, stB(0, 2, t2););
    PHQ(1, 0, 1, 0, stA(0, t2););
    PHQ(1, 1, 0, 0, stB(1, 0, t3););
    PHQ(1, 2, 0, 0, stB(1, 1, t3););
    PHQ(1, 3, 0, 1, stB(1, 2, t3););
  }

  // Epilogue with fused RoPE on Q|K columns (< 2560). Partner value (col^1)
  // lives in lane^1 (adjacent l15) -> one shfl_xor per element.
  const float L2B = 0.20762050593046007f;  // log2(10000)/64
  const int r0 = m0 + wr * 64 + lg * 4;
  const int c0 = n0 + wc * 96 + l15;
  UNROLL for (int n = 0; n < 6; n++) {
    const int col = c0 + n * 16;
    const bool rope = col < 2560;
    const float inv = exp2f(-(float)((col & 127) >> 1) * L2B);
    UNROLL for (int m = 0; m < 4; m++)
      UNROLL for (int i = 0; i < 4; i++) {
        float v = acc[m][n][i];
        float p = __shfl_xor(v, 1);
        float outv = v;
        if (rope) {
          int t = (r0 + m * 16 + i) & (T_SEQ - 1);
          float cs, sn;
          __sincosf((float)t * inv, &sn, &cs);
          outv = (col & 1) ? (p * sn + v * cs) : (v * cs - p * sn);
        }
        C[(size_t)(r0 + m * 16 + i) * N + col] = (bf16)outv;
      }
  }
}

// ---------------- GEMM B: 256x128 8-phase (full-machine grid for out-proj) ------
#define PH2(BUF, P, RB, VMW, STAGE) do {                                                  \
    bf16x8 a0k0 = rdA(BUF, 2*(P),     0), a0k1 = rdA(BUF, 2*(P),     1);                  \
    bf16x8 a1k0 = rdA(BUF, 2*(P) + 1, 0), a1k1 = rdA(BUF, 2*(P) + 1, 1);                  \
    if (RB) {                                                                             \
      UNROLL for (int n = 0; n < 2; n++) { b0[n] = rdB(BUF, 0, n); b1[n] = rdB(BUF, 1, n); } \
    }                                                                                     \
    STAGE                                                                                 \
    __builtin_amdgcn_sched_barrier(0);                                                    \
    __builtin_amdgcn_s_barrier();                                                         \
    asm volatile("s_waitcnt lgkmcnt(0)" ::: "memory");                                    \
    __builtin_amdgcn_sched_barrier(0);                                                    \
    __builtin_amdgcn_s_setprio(1);                                                        \
    UNROLL for (int n = 0; n < 2; n++) {                                                  \
      acc[2*(P)][n]   = __builtin_amdgcn_mfma_f32_16x16x32_bf16(a0k0, b0[n], acc[2*(P)][n], 0, 0, 0);     \
      acc[2*(P)][n]   = __builtin_amdgcn_mfma_f32_16x16x32_bf16(a0k1, b1[n], acc[2*(P)][n], 0, 0, 0);     \
      acc[2*(P)+1][n] = __builtin_amdgcn_mfma_f32_16x16x32_bf16(a1k0, b0[n], acc[2*(P)+1][n], 0, 0, 0);   \
      acc[2*(P)+1][n] = __builtin_amdgcn_mfma_f32_16x16x32_bf16(a1k1, b1[n], acc[2*(P)+1][n], 0, 0, 0);   \
    }                                                                                     \
    __builtin_amdgcn_s_setprio(0);                                                        \
    if (VMW) { asm volatile("s_waitcnt vmcnt(2)" ::: "memory"); }                         \
    __builtin_amdgcn_sched_barrier(0);                                                    \
    __builtin_amdgcn_s_barrier();                                                         \
  } while (0)

__global__ __launch_bounds__(512) void k_gemm3(const bf16* __restrict__ A,
                                               const bf16* __restrict__ BT,
                                               float* __restrict__ C,
                                               int M, int N, int K) {
  __shared__ __align__(16) bf16 L[2][3][8192];     // [buf][A0,A1,B][128*64]
  const int nwg = gridDim.x * gridDim.y;
  const int orig = blockIdx.y * gridDim.x + blockIdx.x;
  const int tile = (orig & 7) * (nwg >> 3) + (orig >> 3);   // nwg % 8 == 0
  const int m0 = (tile % gridDim.x) * 256, n0 = (tile / gridDim.x) * 128;
  const int tid = threadIdx.x;
  const int lane = tid & 63, w = tid >> 6;
  const int wr = w >> 2, wc = w & 3;
  const int l15 = lane & 15, lg = lane >> 4;
  const int srow = tid >> 3;
  const int scol = ((tid & 7) ^ (srow & 7)) * 8;
  const int NKT = K >> 6;

  f32x4 acc[8][2] = {};
  bf16x8 b0[2], b1[2];

  auto stA = [&](int buf, int half, int kt) {
    const bf16* g = A + (size_t)(m0 + half * 128 + srow) * K + kt * 64 + scol;
    bf16* lb = &L[buf][half][w * 512];
    gload_lds16(g, lb);
    gload_lds16(g + (size_t)64 * K, lb + 4096);
  };
  auto stB = [&](int buf, int kt) {
    const bf16* g = BT + (size_t)(n0 + srow) * K + kt * 64 + scol;
    bf16* lb = &L[buf][2][w * 512];
    gload_lds16(g, lb);
    gload_lds16(g + (size_t)64 * K, lb + 4096);
  };
  auto rdA = [&](int buf, int fr, int kk) -> bf16x8 {
    int r = fr * 16 + l15;
    return *(const bf16x8*)((const char*)&L[buf][wr][0] + r * 128 +
                            (((kk * 4 + lg) ^ (r & 7)) << 4));
  };
  auto rdB = [&](int buf, int kk, int n) -> bf16x8 {
    int rr = wc * 32 + n * 16 + l15;
    return *(const bf16x8*)((const char*)&L[buf][2][0] + rr * 128 +
                            (((kk * 4 + lg) ^ (rr & 7)) << 4));
  };

  stA(0, 0, 0); stA(0, 1, 0); stB(0, 0);
  stB(1, 1);
  asm volatile("s_waitcnt vmcnt(2)" ::: "memory");
  __builtin_amdgcn_sched_barrier(0);
  __builtin_amdgcn_s_barrier();

  for (int it = 0; it < (NKT >> 1); ++it) {
    const int t1 = 2 * it + 1;
    const int t2 = (t1 + 1 < NKT) ? t1 + 1 : NKT - 1;
    const int t3 = (t1 + 2 < NKT) ? t1 + 2 : NKT - 1;
    PH2(0, 0, 1, 0, stA(1, 0, t1););
    PH2(0, 1, 0, 0, stA(1, 1, t1););
    PH2(0, 2, 0, 0, stB(0, t2););
    PH2(0, 3, 0, 1, ;);
    PH2(1, 0, 1, 0, stA(0, 0, t2););
    PH2(1, 1, 0, 0, stA(0, 1, t2););
    PH2(1, 2, 0, 0, stB(1, t3););
    PH2(1, 3, 0, 1, ;);
  }

  const int r0 = m0 + wr * 128 + lg * 4;
  const int c0 = n0 + wc * 32 + l15;
  UNROLL for (int m = 0; m < 8; m++)
    UNROLL for (int n = 0; n < 2; n++)
      UNROLL for (int i = 0; i < 4; i++)
        C[(size_t)(r0 + m * 16 + i) * N + (c0 + n * 16)] = acc[m][n][i];
}

// ---------------- flash attention (causal, GQA), head-paired, shared-operand ----
// Round-13 configuration VERBATIM (measured best: 83.4 us).
#define COMPUTE2(kt) do {                                                                 \
    f32x4 sA_[4] = {}, sB_[4] = {};                                                       \
    const char* ks_ = (const char*)Ks;                                                    \
    __builtin_amdgcn_s_setprio(1);                                                        \
    UNROLL for (int kk = 0; kk < 4; kk++)                                                 \
      UNROLL for (int n = 0; n < 4; n++) {                                                \
        int row_ = n * 16 + l15;                                                          \
        int cb_ = (kk * 64 + lg * 16) ^ ((row_ & 7) << 4);                                \
        bf16x8 kf_ = *(const bf16x8*)(ks_ + row_ * 256 + cb_);                            \
        sA_[n] = __builtin_amdgcn_mfma_f32_16x16x32_bf16(kf_, qA[kk], sA_[n], 0, 0, 0);   \
        sB_[n] = __builtin_amdgcn_mfma_f32_16x16x32_bf16(kf_, qB[kk], sB_[n], 0, 0, 0);   \
      }                                                                                   \
    __builtin_amdgcn_s_setprio(0);                                                        \
    __syncthreads();                       /* bar1: QK reads done, V(kt) landed */        \
    if ((kt) + 1 < NT) issueK((kt) + 1);   /* refill Ks; flies under SM+PV */             \
    float vmA_ = -1e30f, vmB_ = -1e30f;                                                   \
    if ((kt) == qt) {                                                                     \
      UNROLL for (int n = 0; n < 4; n++)                                                  \
        UNROLL for (int i = 0; i < 4; i++) {                                              \
          if ((kt) * 64 + n * 16 + lg * 4 + i > qglob) {                                  \
            sA_[n][i] = -1e30f; sB_[n][i] = -1e30f;                                       \
          }                                                                               \
          vmA_ = fmaxf(vmA_, sA_[n][i]);                                                  \
          vmB_ = fmaxf(vmB_, sB_[n][i]);                                                  \
        }                                                                                 \
    } else {                                                                              \
      UNROLL for (int n = 0; n < 4; n++)                                                  \
        UNROLL for (int i = 0; i < 4; i++) {                                              \
          vmA_ = fmaxf(vmA_, sA_[n][i]);                                                  \
          vmB_ = fmaxf(vmB_, sB_[n][i]);                                                  \
        }                                                                                 \
    }                                                                                     \
    vmA_ = fmaxf(vmA_, __shfl_xor(vmA_, 16));                                             \
    vmA_ = fmaxf(vmA_, __shfl_xor(vmA_, 32));                                             \
    vmB_ = fmaxf(vmB_, __shfl_xor(vmB_, 16));                                             \
    vmB_ = fmaxf(vmB_, __shfl_xor(vmB_, 32));                                             \
    if (!__all((vmA_ <= mA + 8.0f) && (vmB_ <= mB + 8.0f))) {                             \
      float mnA_ = fmaxf(mA, vmA_), mnB_ = fmaxf(mB, vmB_);                               \
      float alA_ = __builtin_amdgcn_exp2f(mA - mnA_);                                     \
      float alB_ = __builtin_amdgcn_exp2f(mB - mnB_);                                     \
      mA = mnA_; mB = mnB_;                                                               \
      lA *= alA_; lB *= alB_;                                                             \
      UNROLL for (int i = 0; i < 4; i++) {                                                \
        int src_ = (lane & 48) + ((lane >> 2) & 12) + i;                                  \
        float aA_ = __shfl(alA_, src_);                                                   \
        float aB_ = __shfl(alB_, src_);                                                   \
        UNROLL for (int n = 0; n < 8; n++) { oA[n][i] *= aA_; oB[n][i] *= aB_; }          \
      }                                                                                   \
    }                                                                                     \
    bf16x8 paA0_, paA1_, paB0_, paB1_;                                                    \
    {                                                                                     \
      float rs_ = 0.f;                                                                    \
      UNROLL for (int n = 0; n < 4; n++) {                                                \
        bf16x4 pk_;                                                                       \
        UNROLL for (int i = 0; i < 4; i++) {                                              \
          float pv_ = __builtin_amdgcn_exp2f(sA_[n][i] - mA);                             \
          rs_ += pv_;                                                                     \
          pk_[i] = (bf16)pv_;                                                             \
        }                                                                                 \
        *(bf16x4*)(&Ps[w][l15][n * 16 + lg * 4]) = pk_;                                   \
      }                                                                                   \
      rs_ += __shfl_xor(rs_, 16);                                                         \
      rs_ += __shfl_xor(rs_, 32);                                                         \
      lA += rs_;                                                                          \
      paA0_ = *(const bf16x8*)(&Ps[w][l15][lg * 8]);                                      \
      paA1_ = *(const bf16x8*)(&Ps[w][l15][32 + lg * 8]);                                 \
    }                                                                                     \
    {                                                                                     \
      float rs_ = 0.f;                                                                    \
      UNROLL for (int n = 0; n < 4; n++) {                                                \
        bf16x4 pk_;                                                                       \
        UNROLL for (int i = 0; i < 4; i++) {                                              \
          float pv_ = __builtin_amdgcn_exp2f(sB_[n][i] - mB);                             \
          rs_ += pv_;                                                                     \
          pk_[i] = (bf16)pv_;                                                             \
        }                                                                                 \
        *(bf16x4*)(&Ps[w][l15][n * 16 + lg * 4]) = pk_;                                   \
      }                                                                                   \
      rs_ += __shfl_xor(rs_, 16);                                                         \
      rs_ += __shfl_xor(rs_, 32);                                                         \
      lB += rs_;                                                                          \
      paB0_ = *(const bf16x8*)(&Ps[w][l15][lg * 8]);                                      \
      paB1_ = *(const bf16x8*)(&Ps[w][l15][32 + lg * 8]);                                 \
    }                                                                                     \
    const char* vs_ = (const char*)Vs;                                                    \
    __builtin_amdgcn_s_setprio(1);                                                        \
    UNROLL for (int n = 0; n < 8; n++) {                                                  \
      int d_ = n * 16 + l15;                                                              \
      bf16x8 vf0_ = *(const bf16x8*)(vs_ + d_ * 128 + (((lg) ^ (d_ & 7)) << 4));          \
      oA[n] = __builtin_amdgcn_mfma_f32_16x16x32_bf16(paA0_, vf0_, oA[n], 0, 0, 0);       \
      oB[n] = __builtin_amdgcn_mfma_f32_16x16x32_bf16(paB0_, vf0_, oB[n], 0, 0, 0);       \
      bf16x8 vf1_ = *(const bf16x8*)(vs_ + d_ * 128 + (((4 + lg) ^ (d_ & 7)) << 4));      \
      oA[n] = __builtin_amdgcn_mfma_f32_16x16x32_bf16(paA1_, vf1_, oA[n], 0, 0, 0);       \
      oB[n] = __builtin_amdgcn_mfma_f32_16x16x32_bf16(paB1_, vf1_, oB[n], 0, 0, 0);       \
    }                                                                                     \
    __builtin_amdgcn_s_setprio(0);                                                        \
    __syncthreads();                       /* bar2: PV reads done, K(kt+1) landed */      \
    if ((kt) + 1 < NT) issueV((kt) + 1);   /* refill Vs; flies under next QK */           \
  } while (0)

__global__ __launch_bounds__(256) void k_flash(const bf16* __restrict__ QKV,
                                               const bf16* __restrict__ Vtg,
                                               bf16* __restrict__ AO) {
  __shared__ __align__(16) bf16 Ks[64 * 128];      // [kv row]*256B, chunk XOR (row&7)
  __shared__ __align__(16) bf16 Vs[128 * 64];      // [d row]*128B,  chunk XOR (d&7)
  __shared__ __align__(16) bf16 Ps[4][16][72];     // [q][kv], 144B rows (16B-aligned)
  const int orig = blockIdx.y * 32 + blockIdx.x;
  const int fin  = ((orig & 7) << 6) | (orig >> 3);
  const int bhp  = fin >> 5;                 // b*8 + kvh*2 + hp
  const int qt   = 31 - (fin & 31);
  const int b = bhp >> 3, kvh = (bhp >> 1) & 3, hp = bhp & 1;
  const int h0 = kvh * 4 + hp * 2, h1 = h0 + 1;
  const int tid = threadIdx.x, lane = tid & 63, w = tid >> 6;
  const int l15 = lane & 15, lg = lane >> 4;
  const int qglob = qt * 64 + w * 16 + l15;
  const float qs = 0.12753102f;              // (1/sqrt(128)) * log2(e)

  bf16x8 qA[4], qB[4];
  {
    const size_t qoA = (size_t)(b * T_SEQ + qt * 64 + w * 16 + l15) * NQKV + h0 * DHEAD;
    const size_t qoB = (size_t)(b * T_SEQ + qt * 64 + w * 16 + l15) * NQKV + h1 * DHEAD;
    UNROLL for (int kk = 0; kk < 4; kk++) {
      bf16x8 a = *(const bf16x8*)(QKV + qoA + kk * 32 + lg * 8);
      bf16x8 bb = *(const bf16x8*)(QKV + qoB + kk * 32 + lg * 8);
      UNROLL for (int j = 0; j < 8; j++) {
        a[j] = (bf16)((float)a[j] * qs);
        bb[j] = (bf16)((float)bb[j] * qs);
      }
      qA[kk] = a; qB[kk] = bb;
    }
  }

  f32x4 oA[8] = {}, oB[8] = {};
  float mA = -1e30f, mB = -1e30f, lA = 0.f, lB = 0.f;

  const bf16* Kbase = QKV + (size_t)b * T_SEQ * NQKV + DMODEL + kvh * DHEAD;
  const bf16* Vbase = Vtg + (size_t)(b * 4 + kvh) * 128 * T_SEQ;

  auto issueK = [&](int kt) {
    UNROLL for (int i = 0; i < 4; i++) {
      int row = w * 16 + i * 4 + lg;
      int col = (l15 ^ (row & 7)) * 8;
      gload_lds16(Kbase + (size_t)(kt * 64 + row) * NQKV + col,
                  Ks + (w * 4 + i) * 512);
    }
  };
  auto issueV = [&](int kt) {
    UNROLL for (int i = 0; i < 4; i++) {
      int d = (w * 4 + i) * 8 + (lane >> 3);
      int u = lane & 7;
      gload_lds16(Vbase + (size_t)d * T_SEQ + kt * 64 + ((u ^ (d & 7)) * 8),
                  Vs + (w * 4 + i) * 512);
    }
  };

  issueK(0);
  issueV(0);
  __syncthreads();

  const int NT = qt + 1;
  for (int kt = 0; kt < NT; kt++) {
    COMPUTE2(kt);
  }

  {
    const size_t ob0 = (size_t)(b * T_SEQ + qt * 64 + w * 16 + lg * 4) * DMODEL + h0 * DHEAD + l15;
    const size_t ob1 = (size_t)(b * T_SEQ + qt * 64 + w * 16 + lg * 4) * DMODEL + h1 * DHEAD + l15;
    UNROLL for (int i = 0; i < 4; i++) {
      int src = (lane & 48) + ((lane >> 2) & 12) + i;
      float invA = 1.0f / __shfl(lA, src);
      float invB = 1.0f / __shfl(lB, src);
      UNROLL for (int n = 0; n < 8; n++) {
        AO[ob0 + (size_t)i * DMODEL + n * 16] = (bf16)(oA[n][i] * invA);
        AO[ob1 + (size_t)i * DMODEL + n * 16] = (bf16)(oB[n][i] * invB);
      }
    }
  }
}

extern "C" void kernel_launch(void* const* d_in, const int* in_sizes, int n_in,
                              void* d_out, int out_size, void* d_ws, size_t ws_size,
                              hipStream_t stream) {
  const float* x  = (const float*)d_in[0];
  const float* Wq = (const float*)d_in[1];
  const float* Wk = (const float*)d_in[2];
  const float* Wv = (const float*)d_in[3];
  const float* Wo = (const float*)d_in[4];
  char* ws = (char*)d_ws;
  bf16* xb  = (bf16*)ws;                                             // 4096x2048
  bf16* WT  = (bf16*)(ws + 16777216ull);                             // 3072x2048 (WqT|WkT|WvT)
  bf16* WoT = (bf16*)(ws + 16777216ull + 12582912ull);               // 2048x2048
  bf16* QKV = (bf16*)(ws + 16777216ull + 12582912ull + 8388608ull);  // 4096x3072
  bf16* AO  = (bf16*)(ws + 16777216ull + 12582912ull + 8388608ull + 25165824ull); // 4096x2048
  bf16* Vtg = WT;   // WT is dead after the QKV GEMM; reuse first 4 MB for V^T
  float* out = (float*)d_out;

  k_prep<<<10752, 256, 0, stream>>>(x, Wq, Wk, Wv, Wo, xb, WT, WoT);
  k_gemmQ<<<dim3(32, 8), 512, 0, stream>>>(xb, WT, QKV, 4096, 3072, 2048);
  k_post<<<512, 256, 0, stream>>>(QKV, Vtg);
  k_flash<<<dim3(32, 16), 256, 0, stream>>>(QKV, Vtg, AO);
  k_gemm3<<<dim3(16, 16), 512, 0, stream>>>(AO, WoT, out, 4096, 2048, 2048);
}